// Round 1
// baseline (852.322 us; speedup 1.0000x reference)
//
#include <hip/hip_runtime.h>

#define D 32

// --- Edge aggregation: scatter-add src features into nsum[dst], count deg ---
// 8 threads per edge; each handles a float4 (16B) slice of the 128B row.
__global__ void edge_agg(const float* __restrict__ feat,
                         const int* __restrict__ src,
                         const int* __restrict__ dst,
                         float* __restrict__ nsum,
                         float* __restrict__ deg,
                         int E) {
    int t = blockIdx.x * blockDim.x + threadIdx.x;
    int e = t >> 3;
    int part = t & 7;
    if (e >= E) return;
    int s = src[e];
    int d = dst[e];
    const float4 v = *reinterpret_cast<const float4*>(feat + (size_t)s * D + part * 4);
    float* base = nsum + (size_t)d * D + part * 4;
    atomicAdd(base + 0, v.x);
    atomicAdd(base + 1, v.y);
    atomicAdd(base + 2, v.z);
    atomicAdd(base + 3, v.w);
    if (part == 0) atomicAdd(deg + d, 1.0f);
}

// --- Combine: out[n] = W_self @ feat[n] + W_neigh @ (nsum[n]/max(deg,1)) + b ---
// 32 lanes per node. Lane j computes output feature j.
// W staged in LDS with pitch 33 to avoid 32-way bank conflicts on row reads.
__global__ void combine(const float* __restrict__ feat,
                        const float* __restrict__ nsum,
                        const float* __restrict__ deg,
                        const float* __restrict__ Wself,
                        const float* __restrict__ Wneigh,
                        const float* __restrict__ bias,
                        float* __restrict__ out,
                        int N) {
    __shared__ float sWs[D * 33];
    __shared__ float sWn[D * 33];
    __shared__ float sb[D];
    for (int i = threadIdx.x; i < D * D; i += blockDim.x) {
        int r = i >> 5, c = i & 31;
        sWs[r * 33 + c] = Wself[i];
        sWn[r * 33 + c] = Wneigh[i];
    }
    if (threadIdx.x < D) sb[threadIdx.x] = bias[threadIdx.x];
    __syncthreads();

    int t = blockIdx.x * blockDim.x + threadIdx.x;
    int n = t >> 5;
    int j = t & 31;
    if (n >= N) return;

    float dg = deg[n];
    float inv = 1.0f / fmaxf(dg, 1.0f);

    // Coalesced per-lane loads; broadcast across the 32-lane group via shfl.
    float fj = feat[(size_t)n * D + j];
    float nj = nsum[(size_t)n * D + j] * inv;

    float acc = sb[j];
    const float* wsr = &sWs[j * 33];
    const float* wnr = &sWn[j * 33];
#pragma unroll
    for (int k = 0; k < D; ++k) {
        float fk = __shfl(fj, k, 32);
        float nk = __shfl(nj, k, 32);
        acc += fk * wsr[k] + nk * wnr[k];
    }
    out[(size_t)n * D + j] = acc;
}

extern "C" void kernel_launch(void* const* d_in, const int* in_sizes, int n_in,
                              void* d_out, int out_size, void* d_ws, size_t ws_size,
                              hipStream_t stream) {
    const float* feat   = (const float*)d_in[0];
    const float* Wself  = (const float*)d_in[1];
    const float* Wneigh = (const float*)d_in[2];
    const float* bnb    = (const float*)d_in[3];
    const int*   src    = (const int*)d_in[4];
    const int*   dst    = (const int*)d_in[5];

    int N = in_sizes[0] / D;   // 100000
    int E = in_sizes[4];       // 1600000

    float* nsum = (float*)d_ws;                    // N*32 floats
    float* deg  = nsum + (size_t)N * D;            // N floats

    // Zero the accumulators (workspace is poisoned to 0xAA before each call).
    hipMemsetAsync(d_ws, 0, (size_t)N * (D + 1) * sizeof(float), stream);

    // Edge scatter-add: 8 threads per edge.
    long long tE = (long long)E * 8;
    int blkE = 256;
    int grdE = (int)((tE + blkE - 1) / blkE);
    edge_agg<<<grdE, blkE, 0, stream>>>(feat, src, dst, nsum, deg, E);

    // Combine: 32 threads per node.
    long long tN = (long long)N * D;
    int blkN = 256;
    int grdN = (int)((tN + blkN - 1) / blkN);
    combine<<<grdN, blkN, 0, stream>>>(feat, nsum, deg, Wself, Wneigh, bnb,
                                       (float*)d_out, N);
}

// Round 2
// 363.657 us; speedup vs baseline: 2.3438x; 2.3438x over previous
//
#include <hip/hip_runtime.h>

#define D 32

// ---------- Pass 1: histogram of dst ----------
__global__ void hist_dst(const int* __restrict__ dst, int* __restrict__ counts, int E) {
    int e = blockIdx.x * blockDim.x + threadIdx.x;
    if (e < E) atomicAdd(&counts[dst[e]], 1);
}

// ---------- Pass 2a: per-block exclusive scan of counts ----------
__global__ void scan_level_a(const int* __restrict__ counts, int* __restrict__ offsets,
                             int* __restrict__ bs, int N) {
    __shared__ int tmp[256];
    int t = threadIdx.x;
    int i = blockIdx.x * 256 + t;
    int v = (i < N) ? counts[i] : 0;
    tmp[t] = v;
    __syncthreads();
    for (int off = 1; off < 256; off <<= 1) {
        int add = (t >= off) ? tmp[t - off] : 0;
        __syncthreads();
        tmp[t] += add;
        __syncthreads();
    }
    if (i < N) offsets[i] = tmp[t] - v;       // exclusive within block
    if (t == 255) bs[blockIdx.x] = tmp[255];  // block total
}

// ---------- Pass 2b: scan the block sums (single block) ----------
__global__ void scan_level_b(int* __restrict__ bs, int nB) {
    __shared__ int tmp[1024];
    int t = threadIdx.x;
    int v = (t < nB) ? bs[t] : 0;
    tmp[t] = v;
    __syncthreads();
    for (int off = 1; off < 1024; off <<= 1) {
        int add = (t >= off) ? tmp[t - off] : 0;
        __syncthreads();
        tmp[t] += add;
        __syncthreads();
    }
    if (t < nB) bs[t] = tmp[t] - v;  // exclusive
}

// ---------- Pass 2c: add block offsets, produce offsets + mutable cursor ----------
__global__ void scan_level_c(int* __restrict__ offsets, int* __restrict__ cursor,
                             const int* __restrict__ bs, int N) {
    int i = blockIdx.x * 256 + threadIdx.x;
    if (i < N) {
        int o = offsets[i] + bs[blockIdx.x];
        offsets[i] = o;
        cursor[i] = o;
    }
}

// ---------- Pass 3: bucket src ids by dst ----------
__global__ void scatter_edges(const int* __restrict__ src, const int* __restrict__ dst,
                              int* __restrict__ cursor, int* __restrict__ ssrc, int E) {
    int e = blockIdx.x * blockDim.x + threadIdx.x;
    if (e < E) {
        int pos = atomicAdd(&cursor[dst[e]], 1);
        ssrc[pos] = src[e];
    }
}

// ---------- Pass 4: fused gather-mean + combine ----------
// 32 lanes per node; lane j owns feature/column j.
__global__ void gather_combine(const float* __restrict__ feat,
                               const int* __restrict__ ssrc,
                               const int* __restrict__ offsets,
                               const int* __restrict__ counts,
                               const float* __restrict__ Wself,
                               const float* __restrict__ Wneigh,
                               const float* __restrict__ bias,
                               float* __restrict__ out,
                               int N) {
    __shared__ float sWs[D * 33];
    __shared__ float sWn[D * 33];
    __shared__ float sb[D];
    for (int i = threadIdx.x; i < D * D; i += blockDim.x) {
        int r = i >> 5, c = i & 31;
        sWs[r * 33 + c] = Wself[i];
        sWn[r * 33 + c] = Wneigh[i];
    }
    if (threadIdx.x < D) sb[threadIdx.x] = bias[threadIdx.x];
    __syncthreads();

    int t = blockIdx.x * blockDim.x + threadIdx.x;
    int n = t >> 5;
    int j = t & 31;
    if (n >= N) return;

    int start = offsets[n];
    int cnt = counts[n];

    // Gather-sum incoming src rows. Edge ids fetched 32-wide, broadcast via shfl.
    float acc = 0.0f;
    for (int base = 0; base < cnt; base += 32) {
        int m = min(cnt - base, 32);
        int sv = (base + j < cnt) ? ssrc[start + base + j] : 0;
        for (int i = 0; i < m; ++i) {
            int s = __shfl(sv, i, 32);
            acc += feat[(size_t)s * D + j];
        }
    }
    float inv = 1.0f / (float)max(cnt, 1);
    float nj = acc * inv;
    float fj = feat[(size_t)n * D + j];

    float res = sb[j];
    const float* wsr = &sWs[j * 33];
    const float* wnr = &sWn[j * 33];
#pragma unroll
    for (int k = 0; k < D; ++k) {
        float fk = __shfl(fj, k, 32);
        float nk = __shfl(nj, k, 32);
        res += fk * wsr[k] + nk * wnr[k];
    }
    out[(size_t)n * D + j] = res;
}

extern "C" void kernel_launch(void* const* d_in, const int* in_sizes, int n_in,
                              void* d_out, int out_size, void* d_ws, size_t ws_size,
                              hipStream_t stream) {
    const float* feat   = (const float*)d_in[0];
    const float* Wself  = (const float*)d_in[1];
    const float* Wneigh = (const float*)d_in[2];
    const float* bnb    = (const float*)d_in[3];
    const int*   src    = (const int*)d_in[4];
    const int*   dst    = (const int*)d_in[5];

    int N = in_sizes[0] / D;   // 100000
    int E = in_sizes[4];       // 1600000

    // Workspace layout (ints): counts[N] | offsets[N] | cursor[N] | bs[1024] | ssrc[E]
    int* counts  = (int*)d_ws;
    int* offsets = counts + N;
    int* cursor  = offsets + N;
    int* bs      = cursor + N;
    int* ssrc    = bs + 1024;

    hipMemsetAsync(counts, 0, (size_t)N * sizeof(int), stream);

    int grdE = (E + 255) / 256;
    hist_dst<<<grdE, 256, 0, stream>>>(dst, counts, E);

    int nB = (N + 255) / 256;  // 391 — fits the 1024-thread level-b scan
    scan_level_a<<<nB, 256, 0, stream>>>(counts, offsets, bs, N);
    scan_level_b<<<1, 1024, 0, stream>>>(bs, nB);
    scan_level_c<<<nB, 256, 0, stream>>>(offsets, cursor, bs, N);

    scatter_edges<<<grdE, 256, 0, stream>>>(src, dst, cursor, ssrc, E);

    int grdN = ((long long)N * D + 255) / 256;
    gather_combine<<<grdN, 256, 0, stream>>>(feat, ssrc, offsets, counts,
                                             Wself, Wneigh, bnb, (float*)d_out, N);
}